// Round 16
// baseline (109.508 us; speedup 1.0000x reference)
//
#include <hip/hip_runtime.h>

typedef _Float16 f16x8 __attribute__((ext_vector_type(8)));
typedef float f32x4 __attribute__((ext_vector_type(4)));
typedef unsigned int u32x4 __attribute__((ext_vector_type(4)));

#define D_DIM 256
#define K_CL  128
#define WR    32           // rows per wave-tile (two 16-row groups share B)
#define MARGIN 0.1f        // verified r5/r7/r8/r11-r15 (0.05 escaped in r10)

__device__ __forceinline__ unsigned pkf16(float a, float b) {
  return __builtin_bit_cast(unsigned, __builtin_amdgcn_cvt_pkrtz(a, b));
}

// ---- prep: B fp16 MFMA-fragment image (64KB) + numpy-exact csq (512B) -> d_ws.
// chunk ch=ct*8+k (1KB): lane l holds cen[ct*16+(l&15)][k*32+(l>>4)*8 .. +8].
extern "C" __global__ void __launch_bounds__(64)
k_prep(const float* __restrict__ cen, unsigned int* __restrict__ bfr,
       float* __restrict__ csq_g)
{
  const int b = blockIdx.x;      // chunk id 0..63
  const int l = threadIdx.x;
  const int l15 = l & 15, g = l >> 4;
  const int ct = b >> 3, k = b & 7;
  const float* cp = cen + (size_t)((ct << 4) + l15) * D_DIM + (k << 5) + (g << 3);
  const float4 v0 = *(const float4*)(cp);
  const float4 v1 = *(const float4*)(cp + 4);
  *(u32x4*)((char*)bfr + (b << 10) + (l << 4)) =
      (u32x4){pkf16(v0.x, v0.y), pkf16(v0.z, v0.w),
              pkf16(v1.x, v1.y), pkf16(v1.z, v1.w)};
  if (b < 4) {   // csqnp for clusters b*32..b*32+31 (verified r12 pattern)
#pragma clang fp contract(off)
    float blk0 = 0.f, blk1 = 0.f;
    const int c = (b << 5) + (l >> 1), sub = l & 1;
    const float* a = cen + (size_t)c * D_DIM + (sub << 2);
#pragma unroll
    for (int b2 = 0; b2 < 2; ++b2) {
      const float* ab = a + (b2 << 7);
      const float4 w0 = *(const float4*)(ab);
      float v[4] = {w0.x * w0.x, w0.y * w0.y, w0.z * w0.z, w0.w * w0.w};
      for (int i = 1; i < 16; ++i) {
        const float4 vi = *(const float4*)(ab + (i << 3));
        v[0] = v[0] + vi.x * vi.x; v[1] = v[1] + vi.y * vi.y;
        v[2] = v[2] + vi.z * vi.z; v[3] = v[3] + vi.w * vi.w;
      }
      const float part = (v[0] + v[1]) + (v[2] + v[3]);
      if (b2 == 0) blk0 = part; else blk1 = part;
    }
    const float o0 = __shfl_xor(blk0, 1);
    const float o1 = __shfl_xor(blk1, 1);
    if (sub == 0) csq_g[c] = (blk0 + o0) + (blk1 + o1);
  }
}

// ---- main: zero block barriers. Each wave = one 32-row tile (two 16-row
// groups). Per k-step: 4 z float4-pairs + 8 B fragment loads (independent)
// feed 16 MFMAs — 2 MFMAs per B load (B L2 traffic halved vs WR=16), deep
// load batches for latency hiding. zsq accumulated fp32 in-loop (per-row-
// const error cancels in ranking/gap). In-register two-smallest+sum epilogue;
// s from quantized keys. Ambiguous rows (gap<MARGIN) refined wave-locally
// (numpy-fp32-emulating pipeline, ops bit-identical to r3-verified).
extern "C" __global__ void __launch_bounds__(256)
k_main(const float* __restrict__ z, const float* __restrict__ cen,
       const unsigned int* __restrict__ bfr, const float* __restrict__ csq_g,
       float* __restrict__ s_out, float* __restrict__ c_out, int ntiles)
{
  __shared__ __align__(16) float zrow_s[4][D_DIM];   // per-wave refine scratch
  __shared__ float stmp_s[4][K_CL];

  const int tid = threadIdx.x;
  const int w   = tid >> 6;      // wave 0..3
  const int l   = tid & 63;
  const int l15 = l & 15;
  const int g   = l >> 4;

  const int t = (blockIdx.x << 2) + w;
  if (t >= ntiles) return;
  const int row0 = t << 5;

  float csqv[8];
#pragma unroll
  for (int ct = 0; ct < 8; ++ct) csqv[ct] = csq_g[(ct << 4) + l15];

  // ---- fused loop: per k-step, z(2 groups) + B(8 chunks) loads -> 16 MFMAs.
  f32x4 acc[2][8];
#pragma unroll
  for (int gr = 0; gr < 2; ++gr)
#pragma unroll
    for (int ct = 0; ct < 8; ++ct) acc[gr][ct] = (f32x4){0.f, 0.f, 0.f, 0.f};
  float zs0 = 0.f, zs1 = 0.f;
  const float* zr0 = z + (size_t)(row0 + l15) * D_DIM + (g << 3);
  const float* zr1 = zr0 + (size_t)16 * D_DIM;

#pragma unroll
  for (int k = 0; k < 8; ++k) {
    const float4 a0 = *(const float4*)(zr0 + (k << 5));
    const float4 a1 = *(const float4*)(zr0 + (k << 5) + 4);
    const float4 b0 = *(const float4*)(zr1 + (k << 5));
    const float4 b1 = *(const float4*)(zr1 + (k << 5) + 4);
    u32x4 bb[8];
#pragma unroll
    for (int ct = 0; ct < 8; ++ct)
      bb[ct] = *(const u32x4*)((const char*)bfr + (((ct << 3) + k) << 10) + (l << 4));
    const f16x8 az0 = __builtin_bit_cast(f16x8,
        (u32x4){pkf16(a0.x, a0.y), pkf16(a0.z, a0.w),
                pkf16(a1.x, a1.y), pkf16(a1.z, a1.w)});
    const f16x8 az1 = __builtin_bit_cast(f16x8,
        (u32x4){pkf16(b0.x, b0.y), pkf16(b0.z, b0.w),
                pkf16(b1.x, b1.y), pkf16(b1.z, b1.w)});
    zs0 += a0.x*a0.x + a0.y*a0.y + a0.z*a0.z + a0.w*a0.w
         + a1.x*a1.x + a1.y*a1.y + a1.z*a1.z + a1.w*a1.w;
    zs1 += b0.x*b0.x + b0.y*b0.y + b0.z*b0.z + b0.w*b0.w
         + b1.x*b1.x + b1.y*b1.y + b1.z*b1.z + b1.w*b1.w;
#pragma unroll
    for (int ct = 0; ct < 8; ++ct) {
      const f16x8 bfrag = __builtin_bit_cast(f16x8, bb[ct]);
      acc[0][ct] = __builtin_amdgcn_mfma_f32_16x16x32_f16(az0, bfrag, acc[0][ct], 0, 0, 0);
      acc[1][ct] = __builtin_amdgcn_mfma_f32_16x16x32_f16(az1, bfrag, acc[1][ct], 0, 0, 0);
    }
  }
  zs0 += __shfl_xor(zs0, 16);    // reduce over g: zsq of row l15 (group 0)
  zs0 += __shfl_xor(zs0, 32);
  zs1 += __shfl_xor(zs1, 16);    // zsq of row 16+l15 (group 1)
  zs1 += __shfl_xor(zs1, 32);
  float zsqj[2][4];
#pragma unroll
  for (int j = 0; j < 4; ++j) {
    zsqj[0][j] = __shfl(zs0, (g << 2) + j);   // zsq[4g+j]
    zsqj[1][j] = __shfl(zs1, (g << 2) + j);   // zsq[16+4g+j]
  }

  // ---- epilogue. acc[gr][ct][j] = dot(z[row0+16gr+4g+j], cen[ct*16+l15]).
  unsigned km1[2][4], km2[2][4];
  float rinv[2][4];
#pragma unroll
  for (int gr = 0; gr < 2; ++gr) {
#pragma unroll
    for (int j = 0; j < 4; ++j) {
      unsigned m1 = 0xFFFFFFFFu, m2 = 0xFFFFFFFFu;
      float sum = 0.f;
#pragma unroll
      for (int ct = 0; ct < 8; ++ct) {
        const float sq = fmaxf(fmaf(-2.0f, acc[gr][ct][j], zsqj[gr][j] + csqv[ct]), 0.0f);
        const unsigned u = (__float_as_uint(sq) & 0xFFFFFF80u) | (unsigned)((ct << 4) + l15);
        const unsigned mn = min(m1, u), mx = max(m1, u);
        m1 = mn; m2 = min(m2, mx);
        sum += __builtin_amdgcn_rcpf(
            1.0f + __builtin_amdgcn_sqrtf(__uint_as_float(u & 0xFFFFFF80u)));
      }
#pragma unroll
      for (int m = 1; m <= 8; m <<= 1) {   // butterfly over the 16-lane group
        const unsigned o1 = __shfl_xor(m1, m);
        const unsigned o2 = __shfl_xor(m2, m);
        sum += __shfl_xor(sum, m);
        const unsigned mn = min(m1, o1), mx = max(m1, o1);
        m1 = mn; m2 = min(mx, min(m2, o2));
      }
      km1[gr][j] = m1; km2[gr][j] = m2;
      rinv[gr][j] = __builtin_amdgcn_rcpf(sum);
    }
  }

  // ---- write s (from quantized sq) + c.
#pragma unroll
  for (int gr = 0; gr < 2; ++gr) {
#pragma unroll
    for (int j = 0; j < 4; ++j) {
      const int row = row0 + (gr << 4) + (g << 2) + j;
      float* srow = s_out + (size_t)row * K_CL + l15;
#pragma unroll
      for (int ct = 0; ct < 8; ++ct) {
        const float sq = fmaxf(fmaf(-2.0f, acc[gr][ct][j], zsqj[gr][j] + csqv[ct]), 0.0f);
        const float sqq = __uint_as_float(__float_as_uint(sq) & 0xFFFFFF80u);
        srow[ct << 4] =
            __builtin_amdgcn_rcpf(1.0f + __builtin_amdgcn_sqrtf(sqq)) * rinv[gr][j];
      }
      if (l15 == 0) c_out[row] = (float)(km1[gr][j] & 0x7Fu);
    }
  }

  // ---- ambiguity mask (wave-uniform) + wave-local numpy-emulating refine.
  unsigned rowmask = 0;
#pragma unroll
  for (int gr = 0; gr < 2; ++gr) {
#pragma unroll
    for (int j = 0; j < 4; ++j) {
      const float d1 = __uint_as_float(km1[gr][j] & 0xFFFFFF80u);
      const float d2 = __uint_as_float(km2[gr][j] & 0xFFFFFF80u);
      const unsigned long long b = __ballot(l15 == 0 && (d2 - d1) < MARGIN);
      const int base = (gr << 4) + j;
      rowmask |= (unsigned)(b & 1ull) << base;
      rowmask |= (unsigned)((b >> 16) & 1ull) << (base + 4);
      rowmask |= (unsigned)((b >> 32) & 1ull) << (base + 8);
      rowmask |= (unsigned)((b >> 48) & 1ull) << (base + 12);
    }
  }

  while (rowmask) {
    const int r = __builtin_ctz(rowmask);
    rowmask &= rowmask - 1;
    const int grow = row0 + r;
    float* zrs = &zrow_s[w][0];
    float* sts = &stmp_s[w][0];
    *(float4*)(zrs + (l << 2)) =
        *(const float4*)(z + (size_t)grow * D_DIM + (l << 2));
    asm volatile("s_waitcnt lgkmcnt(0)" ::: "memory");
    // numpy-exact zsq (8-accumulator pattern, 8 lanes)
    float zblk = 0.f;
    if (l < 8) {
#pragma clang fp contract(off)
      float b0 = 0.f, b1 = 0.f;
      for (int b2 = 0; b2 < 2; ++b2) {
        const float* ab = zrs + (b2 << 7);
        float x = ab[l];
        float racc = x * x;
        for (int i = 1; i < 16; ++i) { x = ab[(i << 3) + l]; racc = racc + x * x; }
        racc = racc + __shfl_xor(racc, 1);
        racc = racc + __shfl_xor(racc, 2);
        racc = racc + __shfl_xor(racc, 4);
        if (b2 == 0) b0 = racc; else b1 = racc;
      }
      zblk = b0 + b1;
    }
    const float zsq_np = __shfl(zblk, 0);
    // fp64 dots: lane l -> clusters l and l+64 (reassoc ~1e-13 << 1.7e-4
    // fp32 s_tmp tie quantum).
    double d0 = 0.0, d1d = 0.0;
    const float* c0 = cen + (size_t)l * D_DIM;
    const float* c1 = cen + (size_t)(l + 64) * D_DIM;
    for (int d4 = 0; d4 < 64; ++d4) {
      const float4 zv = *(const float4*)(zrs + (d4 << 2));
      const float4 a0 = *(const float4*)(c0 + (d4 << 2));
      const float4 a1 = *(const float4*)(c1 + (d4 << 2));
      d0  += (double)zv.x * a0.x; d0  += (double)zv.y * a0.y;
      d0  += (double)zv.z * a0.z; d0  += (double)zv.w * a0.w;
      d1d += (double)zv.x * a1.x; d1d += (double)zv.y * a1.y;
      d1d += (double)zv.z * a1.z; d1d += (double)zv.w * a1.w;
    }
    float st0, st1;
    {
#pragma clang fp contract(off)
      const float dotf0 = (float)d0;
      const float sq0 = (zsq_np + csq_g[l]) - 2.0f * dotf0;
      st0 = 1.0f / (1.0f + sqrtf(fmaxf(sq0, 0.0f)));       // np pow -1 path
      const float dotf1 = (float)d1d;
      const float sq1 = (zsq_np + csq_g[l + 64]) - 2.0f * dotf1;
      st1 = 1.0f / (1.0f + sqrtf(fmaxf(sq1, 0.0f)));
    }
    sts[l] = st0;
    sts[l + 64] = st1;
    asm volatile("s_waitcnt lgkmcnt(0)" ::: "memory");
    // numpy-exact sum of stmp[128]
    float sblk = 0.f;
    if (l < 8) {
#pragma clang fp contract(off)
      float racc = sts[l];
      for (int i = 1; i < 16; ++i) racc = racc + sts[(i << 3) + l];
      racc = racc + __shfl_xor(racc, 1);
      racc = racc + __shfl_xor(racc, 2);
      racc = racc + __shfl_xor(racc, 4);
      sblk = racc;
    }
    const float ssum = __shfl(sblk, 0);
    const float s0 = st0 / ssum;   // IEEE div, like np
    const float s1 = st1 / ssum;
    unsigned long long k0 =
        ((unsigned long long)(0x7FFFFFFFu - __float_as_uint(s0)) << 32) | (unsigned)l;
    unsigned long long k1 =
        ((unsigned long long)(0x7FFFFFFFu - __float_as_uint(s1)) << 32) | (unsigned)(l + 64);
    unsigned long long kk = k0 < k1 ? k0 : k1;   // lower index wins ties
#pragma unroll
    for (int m = 1; m < 64; m <<= 1) {
      const unsigned long long o = __shfl_xor(kk, m);
      kk = o < kk ? o : kk;
    }
    if (l == 0) c_out[grow] = (float)(unsigned)(kk & 0x7Fu);
  }
}

extern "C" void kernel_launch(void* const* d_in, const int* in_sizes, int n_in,
                              void* d_out, int out_size, void* d_ws, size_t ws_size,
                              hipStream_t stream) {
  const float* z   = (const float*)d_in[0];
  const float* cen = (const float*)d_in[1];
  const int M = in_sizes[0] / D_DIM;   // 131072
  float* s_out = (float*)d_out;
  float* c_out = s_out + (size_t)M * K_CL;
  const int ntiles = M / WR;           // 4096 wave-tiles

  unsigned int* bfr = (unsigned int*)d_ws;             // 64KB fragment image
  float* csq_g = (float*)((char*)d_ws + 65536);        // 512B csq table

  hipLaunchKernelGGL(k_prep, dim3(64), dim3(64), 0, stream, cen, bfr, csq_g);
  hipLaunchKernelGGL(k_main, dim3(ntiles / 4), dim3(256), 0, stream,
                     z, cen, bfr, csq_g, s_out, c_out, ntiles);
}

// Round 17
// 80.820 us; speedup vs baseline: 1.3550x; 1.3550x over previous
//
#include <hip/hip_runtime.h>

typedef _Float16 f16x8 __attribute__((ext_vector_type(8)));
typedef float f32x4 __attribute__((ext_vector_type(4)));
typedef unsigned int u32x4 __attribute__((ext_vector_type(4)));

#define D_DIM 256
#define K_CL  128
#define WR    16           // rows per wave-tile
#define MARGIN 0.1f        // verified r5/r7/r8/r11-r16 (0.05 escaped in r10)

__device__ __forceinline__ unsigned pkf16(float a, float b) {
  return __builtin_bit_cast(unsigned, __builtin_amdgcn_cvt_pkrtz(a, b));
}

// ---- prep: B fp16 MFMA-fragment image (64KB) + numpy-exact csq (512B) -> d_ws.
// chunk ch=ct*8+k (1KB): lane l holds cen[ct*16+(l&15)][k*32+(l>>4)*8 .. +8].
extern "C" __global__ void __launch_bounds__(64)
k_prep(const float* __restrict__ cen, unsigned int* __restrict__ bfr,
       float* __restrict__ csq_g)
{
  const int b = blockIdx.x;      // chunk id 0..63
  const int l = threadIdx.x;
  const int l15 = l & 15, g = l >> 4;
  const int ct = b >> 3, k = b & 7;
  const float* cp = cen + (size_t)((ct << 4) + l15) * D_DIM + (k << 5) + (g << 3);
  const float4 v0 = *(const float4*)(cp);
  const float4 v1 = *(const float4*)(cp + 4);
  *(u32x4*)((char*)bfr + (b << 10) + (l << 4)) =
      (u32x4){pkf16(v0.x, v0.y), pkf16(v0.z, v0.w),
              pkf16(v1.x, v1.y), pkf16(v1.z, v1.w)};
  if (b < 4) {   // csqnp for clusters b*32..b*32+31 (verified r12 pattern)
#pragma clang fp contract(off)
    float blk0 = 0.f, blk1 = 0.f;
    const int c = (b << 5) + (l >> 1), sub = l & 1;
    const float* a = cen + (size_t)c * D_DIM + (sub << 2);
#pragma unroll
    for (int b2 = 0; b2 < 2; ++b2) {
      const float* ab = a + (b2 << 7);
      const float4 w0 = *(const float4*)(ab);
      float v[4] = {w0.x * w0.x, w0.y * w0.y, w0.z * w0.z, w0.w * w0.w};
      for (int i = 1; i < 16; ++i) {
        const float4 vi = *(const float4*)(ab + (i << 3));
        v[0] = v[0] + vi.x * vi.x; v[1] = v[1] + vi.y * vi.y;
        v[2] = v[2] + vi.z * vi.z; v[3] = v[3] + vi.w * vi.w;
      }
      const float part = (v[0] + v[1]) + (v[2] + v[3]);
      if (b2 == 0) blk0 = part; else blk1 = part;
    }
    const float o0 = __shfl_xor(blk0, 1);
    const float o1 = __shfl_xor(blk1, 1);
    if (sub == 0) csq_g[c] = (blk0 + o0) + (blk1 + o1);
  }
}

// ---- main: zero block barriers; 4-wave blocks (finer scheduling, 8/CU).
// Each wave = one 16-row tile. z converted IN-LOOP (no persistent az[8] ->
// VGPR ~52-56 -> 9-10 waves/SIMD residency; r16 proved deep-ILP/VGPR loses
// to TLP). B fragments from global image (L2-hot). fp32 zsq accumulated
// in-loop (per-row-const error cancels in ranking/gap). In-register
// two-smallest+sum epilogue; s from quantized keys. Ambiguous rows
// (gap<MARGIN) refined wave-locally (numpy-fp32-emulating pipeline,
// ops bit-identical to r3-verified).
extern "C" __global__ void __launch_bounds__(256)
k_main(const float* __restrict__ z, const float* __restrict__ cen,
       const unsigned int* __restrict__ bfr, const float* __restrict__ csq_g,
       float* __restrict__ s_out, float* __restrict__ c_out, int ntiles)
{
  __shared__ __align__(16) float zrow_s[4][D_DIM];   // per-wave refine scratch
  __shared__ float stmp_s[4][K_CL];

  const int tid = threadIdx.x;
  const int w   = tid >> 6;      // wave 0..3
  const int l   = tid & 63;
  const int l15 = l & 15;
  const int g   = l >> 4;

  const int t = (blockIdx.x << 2) + w;
  if (t >= ntiles) return;
  const int row0 = t << 4;

  float csqv[8];
#pragma unroll
  for (int ct = 0; ct < 8; ++ct) csqv[ct] = csq_g[(ct << 4) + l15];

  // ---- fused k-loop: z loaded+converted per k-step (no persistent az[8]).
  f32x4 acc[8];
#pragma unroll
  for (int ct = 0; ct < 8; ++ct) acc[ct] = (f32x4){0.f, 0.f, 0.f, 0.f};
  float zs = 0.f;
  const float* zr = z + (size_t)(row0 + l15) * D_DIM + (g << 3);
#pragma unroll
  for (int k = 0; k < 8; ++k) {
    const float4 v0 = *(const float4*)(zr + (k << 5));
    const float4 v1 = *(const float4*)(zr + (k << 5) + 4);
    const f16x8 az = __builtin_bit_cast(f16x8,
        (u32x4){pkf16(v0.x, v0.y), pkf16(v0.z, v0.w),
                pkf16(v1.x, v1.y), pkf16(v1.z, v1.w)});
    zs += v0.x*v0.x + v0.y*v0.y + v0.z*v0.z + v0.w*v0.w
        + v1.x*v1.x + v1.y*v1.y + v1.z*v1.z + v1.w*v1.w;
#pragma unroll
    for (int ct = 0; ct < 8; ++ct) {
      const f16x8 b = __builtin_bit_cast(f16x8,
          *(const u32x4*)((const char*)bfr + (((ct << 3) + k) << 10) + (l << 4)));
      acc[ct] = __builtin_amdgcn_mfma_f32_16x16x32_f16(az, b, acc[ct], 0, 0, 0);
    }
  }
  zs += __shfl_xor(zs, 16);      // reduce over g: all lanes get zsq[row l15]
  zs += __shfl_xor(zs, 32);
  float zsqj[4];
#pragma unroll
  for (int j = 0; j < 4; ++j) zsqj[j] = __shfl(zs, (g << 2) + j);  // zsq[4g+j]

  // ---- epilogue in registers. acc[ct][j] = dot(z[row0+4g+j], cen[ct*16+l15]).
  unsigned km1[4], km2[4];
  float rinv[4];
#pragma unroll
  for (int j = 0; j < 4; ++j) {
    unsigned m1 = 0xFFFFFFFFu, m2 = 0xFFFFFFFFu;
    float sum = 0.f;
#pragma unroll
    for (int ct = 0; ct < 8; ++ct) {
      const float sq = fmaxf(fmaf(-2.0f, acc[ct][j], zsqj[j] + csqv[ct]), 0.0f);
      const unsigned u = (__float_as_uint(sq) & 0xFFFFFF80u) | (unsigned)((ct << 4) + l15);
      const unsigned mn = min(m1, u), mx = max(m1, u);
      m1 = mn; m2 = min(m2, mx);
      sum += __builtin_amdgcn_rcpf(
          1.0f + __builtin_amdgcn_sqrtf(__uint_as_float(u & 0xFFFFFF80u)));
    }
#pragma unroll
    for (int m = 1; m <= 8; m <<= 1) {   // butterfly over the 16-lane group
      const unsigned o1 = __shfl_xor(m1, m);
      const unsigned o2 = __shfl_xor(m2, m);
      sum += __shfl_xor(sum, m);
      const unsigned mn = min(m1, o1), mx = max(m1, o1);
      m1 = mn; m2 = min(mx, min(m2, o2));
    }
    km1[j] = m1; km2[j] = m2;
    rinv[j] = __builtin_amdgcn_rcpf(sum);
  }

  // ---- write s (from quantized sq, as r12/r13/r15) + c.
#pragma unroll
  for (int j = 0; j < 4; ++j) {
    float* srow = s_out + (size_t)(row0 + (g << 2) + j) * K_CL + l15;
#pragma unroll
    for (int ct = 0; ct < 8; ++ct) {
      const float sq = fmaxf(fmaf(-2.0f, acc[ct][j], zsqj[j] + csqv[ct]), 0.0f);
      const float sqq = __uint_as_float(__float_as_uint(sq) & 0xFFFFFF80u);
      srow[ct << 4] =
          __builtin_amdgcn_rcpf(1.0f + __builtin_amdgcn_sqrtf(sqq)) * rinv[j];
    }
    if (l15 == 0) c_out[row0 + (g << 2) + j] = (float)(km1[j] & 0x7Fu);
  }

  // ---- ambiguity mask (wave-uniform) + wave-local numpy-emulating refine.
  unsigned rowmask = 0;
#pragma unroll
  for (int j = 0; j < 4; ++j) {
    const float d1 = __uint_as_float(km1[j] & 0xFFFFFF80u);
    const float d2 = __uint_as_float(km2[j] & 0xFFFFFF80u);
    const unsigned long long b = __ballot(l15 == 0 && (d2 - d1) < MARGIN);
    rowmask |= (unsigned)(b & 1ull) << j;
    rowmask |= (unsigned)((b >> 16) & 1ull) << (4 + j);
    rowmask |= (unsigned)((b >> 32) & 1ull) << (8 + j);
    rowmask |= (unsigned)((b >> 48) & 1ull) << (12 + j);
  }

  while (rowmask) {
    const int r = __builtin_ctz(rowmask);
    rowmask &= rowmask - 1;
    const int grow = row0 + r;
    float* zrs = &zrow_s[w][0];
    float* sts = &stmp_s[w][0];
    *(float4*)(zrs + (l << 2)) =
        *(const float4*)(z + (size_t)grow * D_DIM + (l << 2));
    asm volatile("s_waitcnt lgkmcnt(0)" ::: "memory");
    // numpy-exact zsq (8-accumulator pattern, 8 lanes)
    float zblk = 0.f;
    if (l < 8) {
#pragma clang fp contract(off)
      float b0 = 0.f, b1 = 0.f;
      for (int b2 = 0; b2 < 2; ++b2) {
        const float* ab = zrs + (b2 << 7);
        float x = ab[l];
        float racc = x * x;
        for (int i = 1; i < 16; ++i) { x = ab[(i << 3) + l]; racc = racc + x * x; }
        racc = racc + __shfl_xor(racc, 1);
        racc = racc + __shfl_xor(racc, 2);
        racc = racc + __shfl_xor(racc, 4);
        if (b2 == 0) b0 = racc; else b1 = racc;
      }
      zblk = b0 + b1;
    }
    const float zsq_np = __shfl(zblk, 0);
    // fp64 dots: lane l -> clusters l and l+64 (reassoc ~1e-13 << 1.7e-4
    // fp32 s_tmp tie quantum).
    double d0 = 0.0, d1d = 0.0;
    const float* c0 = cen + (size_t)l * D_DIM;
    const float* c1 = cen + (size_t)(l + 64) * D_DIM;
    for (int d4 = 0; d4 < 64; ++d4) {
      const float4 zv = *(const float4*)(zrs + (d4 << 2));
      const float4 a0 = *(const float4*)(c0 + (d4 << 2));
      const float4 a1 = *(const float4*)(c1 + (d4 << 2));
      d0  += (double)zv.x * a0.x; d0  += (double)zv.y * a0.y;
      d0  += (double)zv.z * a0.z; d0  += (double)zv.w * a0.w;
      d1d += (double)zv.x * a1.x; d1d += (double)zv.y * a1.y;
      d1d += (double)zv.z * a1.z; d1d += (double)zv.w * a1.w;
    }
    float st0, st1;
    {
#pragma clang fp contract(off)
      const float dotf0 = (float)d0;
      const float sq0 = (zsq_np + csq_g[l]) - 2.0f * dotf0;
      st0 = 1.0f / (1.0f + sqrtf(fmaxf(sq0, 0.0f)));       // np pow -1 path
      const float dotf1 = (float)d1d;
      const float sq1 = (zsq_np + csq_g[l + 64]) - 2.0f * dotf1;
      st1 = 1.0f / (1.0f + sqrtf(fmaxf(sq1, 0.0f)));
    }
    sts[l] = st0;
    sts[l + 64] = st1;
    asm volatile("s_waitcnt lgkmcnt(0)" ::: "memory");
    // numpy-exact sum of stmp[128]
    float sblk = 0.f;
    if (l < 8) {
#pragma clang fp contract(off)
      float racc = sts[l];
      for (int i = 1; i < 16; ++i) racc = racc + sts[(i << 3) + l];
      racc = racc + __shfl_xor(racc, 1);
      racc = racc + __shfl_xor(racc, 2);
      racc = racc + __shfl_xor(racc, 4);
      sblk = racc;
    }
    const float ssum = __shfl(sblk, 0);
    const float s0 = st0 / ssum;   // IEEE div, like np
    const float s1 = st1 / ssum;
    unsigned long long k0 =
        ((unsigned long long)(0x7FFFFFFFu - __float_as_uint(s0)) << 32) | (unsigned)l;
    unsigned long long k1 =
        ((unsigned long long)(0x7FFFFFFFu - __float_as_uint(s1)) << 32) | (unsigned)(l + 64);
    unsigned long long kk = k0 < k1 ? k0 : k1;   // lower index wins ties
#pragma unroll
    for (int m = 1; m < 64; m <<= 1) {
      const unsigned long long o = __shfl_xor(kk, m);
      kk = o < kk ? o : kk;
    }
    if (l == 0) c_out[grow] = (float)(unsigned)(kk & 0x7Fu);
  }
}

extern "C" void kernel_launch(void* const* d_in, const int* in_sizes, int n_in,
                              void* d_out, int out_size, void* d_ws, size_t ws_size,
                              hipStream_t stream) {
  const float* z   = (const float*)d_in[0];
  const float* cen = (const float*)d_in[1];
  const int M = in_sizes[0] / D_DIM;   // 131072
  float* s_out = (float*)d_out;
  float* c_out = s_out + (size_t)M * K_CL;
  const int ntiles = M / WR;           // 8192 wave-tiles

  unsigned int* bfr = (unsigned int*)d_ws;             // 64KB fragment image
  float* csq_g = (float*)((char*)d_ws + 65536);        // 512B csq table

  hipLaunchKernelGGL(k_prep, dim3(64), dim3(64), 0, stream, cen, bfr, csq_g);
  hipLaunchKernelGGL(k_main, dim3(ntiles / 4), dim3(256), 0, stream,
                     z, cen, bfr, csq_g, s_out, c_out, ntiles);
}